// Round 6
// baseline (602.336 us; speedup 1.0000x reference)
//
#include <hip/hip_runtime.h>

#define NB 2
#define NG 1024
#define HEIGHT 128
#define WIDTH 128
#define HW (HEIGHT * WIDTH)
#define NSEG 8
#define SEGLEN (NG / NSEG)                 // 128
#define ITEM_STRIDE (8 + (SEGLEN + 1) * 20)  // header + 128 items + trailing slot = 2588 floats
#define E10 4.5399931e-05f                 // exp(-10)
#define NBLK 256

// ws layout (floats)
#define REC_U 0                            // unsorted records: 2048*16
#define REC_S 32768                        // sorted records:   2048*16
#define Z_U   65536                        // unsorted z:       2048
#define ITEMS 67584                        // 16 streams * ITEM_STRIDE = 41408
#define RGBOF 108992                       // rendered rgb: 6*HW = 98304
#define P_ENT 207296                       // 4 entropy partials
#define P_L1D 207300                       // 512 depth-l1 partials
#define P_SSS 207812                       // 192 ssim partials
#define P_SSL 208004                       // 192 rgb-l1 partials
#define BAR_OFF 208256                     // 16 ints of grid-barrier state (memset to 0 in-stream)
// record (16 floats): [0]px [1]py [2]hx [3]hy [4]i00 [5]i01 [6]i11 [7]op [8]c0 [9]c1 [10]c2 [11]z
// item (5 quads): q0=[runT,runR,runG,runB] q1=[runD,px,py,op] q2=[hx,hy,i00,i01] q3=[i11,c0,c1,c2] q4=[z,-,-,-]

// Single-use grid barrier (state zeroed by hipMemsetAsync before each launch).
// Arrival: agent-scope acq_rel RMW by thread 0; release: agent-scope store of gen flag.
// Spin: agent-scope acquire loads + s_sleep(1) (~0.2us poll) -- avoids ROCm's
// __ockl_grid_sync s_sleep(127) backoff that cost ~40us/sync in round 5.
__device__ inline void gbar(int* bar, int id) {
    __syncthreads();
    __threadfence();  // make this block's writes agent-visible (incl. cross-XCD)
    if (threadIdx.x == 0) {
        int* cnt = bar + id * 2;
        int* gen = bar + id * 2 + 1;
        int a = __hip_atomic_fetch_add(cnt, 1, __ATOMIC_ACQ_REL, __HIP_MEMORY_SCOPE_AGENT);
        if (a == NBLK - 1) {
            __hip_atomic_store(gen, 1, __ATOMIC_RELEASE, __HIP_MEMORY_SCOPE_AGENT);
        } else {
            while (__hip_atomic_load(gen, __ATOMIC_ACQUIRE, __HIP_MEMORY_SCOPE_AGENT) == 0) {
                __builtin_amdgcn_s_sleep(1);
            }
        }
    }
    __syncthreads();
    __threadfence();  // invalidate stale L1/L2 so all waves see remote writes
}

__device__ inline float blk_reduce(float v, float* sh) {
    for (int off = 32; off > 0; off >>= 1) v += __shfl_down(v, off, 64);
    int lane = threadIdx.x & 63;
    int w = threadIdx.x >> 6;
    __syncthreads();
    if (lane == 0) sh[w] = v;
    __syncthreads();
    float s = 0.f;
    if (threadIdx.x == 0) {
        int nw = (blockDim.x + 63) >> 6;
        for (int i = 0; i < nw; i++) s += sh[i];
    }
    return s;  // valid on thread 0 only
}

// 256 blocks x 512 threads: 8 waves/block, 1 block/CU always co-resident
// (launch_bounds(512) caps VGPR at 256 -> cooperative launch cannot fail).
__global__ __launch_bounds__(512) void k_all(const float* __restrict__ g,
                                             const float* __restrict__ intr,
                                             const float* __restrict__ trgb,
                                             const float* __restrict__ tgt_d,
                                             float* __restrict__ ws,
                                             float* __restrict__ out) {
    int bid = blockIdx.x;
    int tid = threadIdx.x;
    int* bar = (int*)(ws + BAR_OFF);
    __shared__ float smem[5 * 512];
    __shared__ int simem[256];

    // ---------------- P1: per-gaussian preprocess (blocks 0..3) ----------------
    if (bid < 4) {
        int idx = bid * 512 + tid;  // 0..2047
        int b = idx >> 10;
        const float* row = g + (size_t)idx * 38;
        float mx = row[0], my = row[1], mz = row[2];
        float sx = row[3], sy = row[4], sz = row[5];
        float qw = row[6], qx = row[7], qy = row[8], qz = row[9];
        float op = row[10];
        float sh0 = row[11], sh1 = row[12], sh2 = row[13];
        float fx = intr[b * 9 + 0], fy = intr[b * 9 + 4];
        float cx = intr[b * 9 + 2], cy = intr[b * 9 + 5];

        float z = fmaxf(mz, 1e-4f);
        float px = fx * mx / z + cx;
        float py = fy * my / z + cy;

        float r00 = 1.f - 2.f * (qy * qy + qz * qz), r01 = 2.f * (qx * qy - qw * qz), r02 = 2.f * (qx * qz + qw * qy);
        float r10 = 2.f * (qx * qy + qw * qz), r11 = 1.f - 2.f * (qx * qx + qz * qz), r12 = 2.f * (qy * qz - qw * qx);
        float r20 = 2.f * (qx * qz - qw * qy), r21 = 2.f * (qy * qz + qw * qx), r22 = 1.f - 2.f * (qx * qx + qy * qy);
        float a00 = r00 * sx, a01 = r01 * sy, a02 = r02 * sz;
        float a10_ = r10 * sx, a11 = r11 * sy, a12 = r12 * sz;
        float a20 = r20 * sx, a21 = r21 * sy, a22 = r22 * sz;
        float m00 = a00 * a00 + a01 * a01 + a02 * a02;
        float m01 = a00 * a10_ + a01 * a11 + a02 * a12;
        float m02 = a00 * a20 + a01 * a21 + a02 * a22;
        float m11 = a10_ * a10_ + a11 * a11 + a12 * a12;
        float m12 = a10_ * a20 + a11 * a21 + a12 * a22;
        float m22 = a20 * a20 + a21 * a21 + a22 * a22;

        float zc = fmaxf(mz, 1e-6f);
        float aJ = fx / zc, bJ = -fx * mx / (zc * zc);
        float cJ = fy / zc, dJ = -fy * my / (zc * zc);
        float c00 = aJ * aJ * m00 + 2.f * aJ * bJ * m02 + bJ * bJ * m22 + 0.3f;
        float c01 = cJ * (aJ * m01 + bJ * m12) + dJ * (aJ * m02 + bJ * m22);
        float c11 = cJ * cJ * m11 + 2.f * cJ * dJ * m12 + dJ * dJ * m22 + 0.3f;
        float det = fmaxf(c00 * c11 - c01 * c01, 1e-8f);
        float i00 = c11 / det;
        float i11 = c00 / det;
        float i01 = -c01 / det;

        const float C0c = 0.28209479177387814f;
        float col0 = fminf(fmaxf(sh0 * C0c + 0.5f, 0.f), 1.f);
        float col1 = fminf(fmaxf(sh1 * C0c + 0.5f, 0.f), 1.f);
        float col2 = fminf(fmaxf(sh2 * C0c + 0.5f, 0.f), 1.f);

        float hx = sqrtf(20.f * c00);
        float hy = sqrtf(20.f * c11);

        float* rec = ws + REC_U + (size_t)idx * 16;
        ((float4*)rec)[0] = make_float4(px, py, hx, hy);
        ((float4*)rec)[1] = make_float4(i00, i01, i11, op);
        ((float4*)rec)[2] = make_float4(col0, col1, col2, z);
        ws[Z_U + idx] = z;

        float o = fminf(fmaxf(op, 1e-6f), 1.f - 1e-6f);
        float ent = -(o * logf(o) + (1.f - o) * logf(1.f - o));
        float s = blk_reduce(ent, smem);
        if (tid == 0) ws[P_ENT + bid] = s;
    }
    gbar(bar, 0);

    // ---------------- P2: rank sort + record scatter (blocks 0..3) ----------------
    if (bid < 4) {
        int gi = bid * 512 + tid;
        int b = gi >> 10;
        int i = gi & 1023;
        const float* zb = ws + Z_U + (b << 10);
        float zi = zb[i];
        int rank = 0;
        for (int j = 0; j < NG; j += 4) {
            float4 zq = *(const float4*)(zb + j);
            rank += (zq.x < zi) || (zq.x == zi && (j + 0) < i);
            rank += (zq.y < zi) || (zq.y == zi && (j + 1) < i);
            rank += (zq.z < zi) || (zq.z == zi && (j + 2) < i);
            rank += (zq.w < zi) || (zq.w == zi && (j + 3) < i);
        }
        const float4* src = (const float4*)(ws + REC_U + (size_t)gi * 16);
        float4 r0 = src[0], r1 = src[1], r2 = src[2];
        float4* dst = (float4*)(ws + REC_S + (size_t)((b << 10) + rank) * 16);
        dst[0] = r0; dst[1] = r1; dst[2] = r2;
    }
    gbar(bar, 1);

    // ---------------- P3: item streams via segmented scan (blocks 0..15) ----------------
    if (bid < 16) {
        int s = bid;  // (batch, seg)
        int b = s >> 3, seg = s & 7;
        int k = tid;
        bool lk = (tid < 128);
        float* sT = smem + 0 * 128;
        float* sr = smem + 1 * 128;
        float* sgc = smem + 2 * 128;
        float* sb = smem + 3 * 128;
        float* sd = smem + 4 * 128;
        int* sf = simem;
        int* sx = simem + 128;
        float4 q0, q1, q2;
        bool act = false;
        if (lk) {
            const float* r = ws + REC_S + (size_t)((b << 10) + seg * SEGLEN + k) * 16;
            q0 = ((const float4*)r)[0];  // px py hx hy
            q1 = ((const float4*)r)[1];  // i00 i01 i11 op
            q2 = ((const float4*)r)[2];  // c0 c1 c2 z
            float a10 = E10 * q1.w;
            act = (q0.x + q0.z >= 0.f) && (q0.x - q0.z <= 127.f) &&
                  (q0.y + q0.w >= 0.f) && (q0.y - q0.w <= 127.f);
            if (act) {
                sT[k] = 1.f; sr[k] = 0.f; sgc[k] = 0.f; sb[k] = 0.f; sd[k] = 0.f;
                sf[k] = 1; sx[k] = 1;
            } else {
                sT[k] = 1.f - a10;
                sr[k] = a10 * q2.x; sgc[k] = a10 * q2.y; sb[k] = a10 * q2.z; sd[k] = a10 * q2.w;
                sf[k] = 0; sx[k] = 0;
            }
        }
        __syncthreads();
#pragma unroll
        for (int off = 1; off < 128; off <<= 1) {
            float pT = 1.f, pr = 0.f, pg = 0.f, pb = 0.f, pd = 0.f;
            int pf = 0, px_ = 0;
            bool doit = lk && (k >= off);
            if (doit) {
                pT = sT[k - off]; pr = sr[k - off]; pg = sgc[k - off];
                pb = sb[k - off]; pd = sd[k - off]; pf = sf[k - off]; px_ = sx[k - off];
            }
            __syncthreads();
            if (doit) {
                sx[k] += px_;
                if (!sf[k]) {
                    sr[k] = pr + pT * sr[k];
                    sgc[k] = pg + pT * sgc[k];
                    sb[k] = pb + pT * sb[k];
                    sd[k] = pd + pT * sd[k];
                    sT[k] = pT * sT[k];
                    sf[k] = pf;
                }
            }
            __syncthreads();
        }
        float* so = ws + ITEMS + (size_t)s * ITEM_STRIDE;
        int n = sx[127];
        if (lk && act) {
            float* itp = so + 8 + (size_t)(sx[k] - 1) * 20;
            float rT = 1.f, rr = 0.f, rg = 0.f, rb = 0.f, rd = 0.f;
            if (k > 0) { rT = sT[k - 1]; rr = sr[k - 1]; rg = sgc[k - 1]; rb = sb[k - 1]; rd = sd[k - 1]; }
            ((float4*)itp)[0] = make_float4(rT, rr, rg, rb);
            ((float4*)itp)[1] = make_float4(rd, q0.x, q0.y, q1.w);
            ((float4*)itp)[2] = make_float4(q0.z, q0.w, q1.x, q1.y);
            ((float4*)itp)[3] = make_float4(q1.z, q2.x, q2.y, q2.z);
            ((float4*)itp)[4] = make_float4(q2.w, 0.f, 0.f, 0.f);
        }
        if (tid == 127) {  // trailing run -> slot n (fill all 5 quads so prefetch reads defined data)
            float* itp = so + 8 + (size_t)n * 20;
            ((float4*)itp)[0] = make_float4(sT[127], sr[127], sgc[127], sb[127]);
            ((float4*)itp)[1] = make_float4(sd[127], 0.f, 0.f, 0.f);
            ((float4*)itp)[2] = make_float4(0.f, 0.f, 0.f, 0.f);
            ((float4*)itp)[3] = make_float4(0.f, 0.f, 0.f, 0.f);
            ((float4*)itp)[4] = make_float4(0.f, 0.f, 0.f, 0.f);
        }
        if (tid == 0) ((int*)so)[0] = n;
    }
    gbar(bar, 2);

    // ---------------- P4: render — two 8x8 tiles per block, 8 z-segment waves ----------------
    for (int rep = 0; rep < 2; rep++) {
        int blk = bid + 256 * rep;  // 0..511
        int lane = tid & 63;
        int seg = tid >> 6;
        int b = blk >> 8;
        int t = blk & 255;
        int x0 = (t & 15) * 8, y0 = (t >> 4) * 8;
        int x = x0 + (lane & 7), y = y0 + (lane >> 3);

        const float* base = ws + ITEMS + (size_t)(b * NSEG + seg) * ITEM_STRIDE;
        int n = ((const int*)base)[0];
        const float4* ip = (const float4*)(base + 8);

        float xf = (float)x, yf = (float)y;
        float x0f = (float)x0, x1f = (float)(x0 + 7);
        float y0f = (float)y0, y1f = (float)(y0 + 7);
        float4 a0 = ip[0], a1 = ip[1], a2 = ip[2], a3 = ip[3], a4 = ip[4];
        float T = 1.f, cr = 0.f, cg_ = 0.f, cb = 0.f, cd = 0.f;
        for (int i = 0; i < n; i++) {
            const float4* np = ip + 5;
            float4 b0 = np[0], b1 = np[1], b2 = np[2], b3 = np[3], b4 = np[4];  // prefetch next
            // preceding inactive-run composite
            cr += T * a0.y; cg_ += T * a0.z; cb += T * a0.w; cd += T * a1.x;
            T *= a0.x;
            // active gaussian
            float px = a1.y, py = a1.z, op = a1.w;
            float hx = a2.x, hy = a2.y;
            float alpha;
            if (px + hx >= x0f && px - hx <= x1f && py + hy >= y0f && py - hy <= y1f) {
                float dx = xf - px, dy = yf - py;
                float q = a2.z * dx * dx + 2.f * a2.w * dx * dy + a3.x * dy * dy;
                float pw = fminf(fmaxf(-0.5f * q, -10.f), 0.f);
                alpha = fminf(__expf(pw) * op, 0.99f);
            } else {
                alpha = E10 * op;  // clamped outside its ellipse: pixel-independent
            }
            float w = T * alpha;
            cr += w * a3.y; cg_ += w * a3.z; cb += w * a3.w; cd += w * a4.x;
            T -= w;
            a0 = b0; a1 = b1; a2 = b2; a3 = b3; a4 = b4;
            ip = np;
        }
        // trailing run
        cr += T * a0.y; cg_ += T * a0.z; cb += T * a0.w; cd += T * a1.x;
        T *= a0.x;

        __syncthreads();  // smem reuse boundary
        float(*comb)[512] = (float(*)[512])smem;
        comb[0][tid] = T;
        comb[1][tid] = cr;
        comb[2][tid] = cg_;
        comb[3][tid] = cb;
        comb[4][tid] = cd;
        __syncthreads();

        if (tid < 64) {
            float T0 = comb[0][tid], r0 = comb[1][tid], g0 = comb[2][tid];
            float b0 = comb[3][tid], d0 = comb[4][tid];
#pragma unroll
            for (int sgi = 1; sgi < NSEG; sgi++) {
                int j = sgi * 64 + tid;
                r0 += T0 * comb[1][j];
                g0 += T0 * comb[2][j];
                b0 += T0 * comb[3][j];
                d0 += T0 * comb[4][j];
                T0 *= comb[0][j];
            }
            r0 = fminf(fmaxf(r0, 0.f), 1.f);
            g0 = fminf(fmaxf(g0, 0.f), 1.f);
            b0 = fminf(fmaxf(b0, 0.f), 1.f);
            float* rgb = ws + RGBOF;
            rgb[((b * 3 + 0) * HEIGHT + y) * WIDTH + x] = r0;
            rgb[((b * 3 + 1) * HEIGHT + y) * WIDTH + x] = g0;
            rgb[((b * 3 + 2) * HEIGHT + y) * WIDTH + x] = b0;
            float l1d = fabsf(d0 - tgt_d[(b * HEIGHT + y) * WIDTH + x]);
            for (int off = 32; off > 0; off >>= 1) l1d += __shfl_down(l1d, off, 64);
            if (tid == 0) ws[P_L1D + blk] = l1d;
        }
        __syncthreads();  // comb fully consumed before next rep overwrites
    }
    gbar(bar, 3);

    // ---------------- P5: SSIM + rgb L1 (blocks 0..191) ----------------
    if (bid < 192) {
        int idx = bid * 512 + tid;  // < 98304 exact
        const float* img1 = ws + RGBOF;
        int bc = idx >> 14;
        int pix = idx & (HW - 1);
        int y = pix >> 7, x = pix & 127;

        float gg[7];
        float gs = 0.f;
#pragma unroll
        for (int i = 0; i < 7; i++) {
            float c = (float)(i - 3);
            gg[i] = __expf(-c * c / 4.5f);
            gs += gg[i];
        }
#pragma unroll
        for (int i = 0; i < 7; i++) gg[i] /= gs;

        float mu1 = 0.f, mu2 = 0.f, s11 = 0.f, s22 = 0.f, s12 = 0.f;
        int plane = bc * HW;
#pragma unroll
        for (int dy = -3; dy <= 3; dy++) {
            int yy = y + dy;
#pragma unroll
            for (int dx = -3; dx <= 3; dx++) {
                int xx = x + dx;
                float w = gg[dy + 3] * gg[dx + 3];
                float i1 = 0.f, i2 = 0.f;
                if (yy >= 0 && yy < HEIGHT && xx >= 0 && xx < WIDTH) {
                    int o = plane + yy * WIDTH + xx;
                    i1 = img1[o];
                    i2 = trgb[o];
                }
                mu1 += w * i1;
                mu2 += w * i2;
                s11 += w * i1 * i1;
                s22 += w * i2 * i2;
                s12 += w * i1 * i2;
            }
        }
        float v1 = s11 - mu1 * mu1;
        float v2 = s22 - mu2 * mu2;
        float cv = s12 - mu1 * mu2;
        const float C1 = 1e-4f, C2 = 9e-4f;
        float ssim = ((2.f * mu1 * mu2 + C1) * (2.f * cv + C2)) /
                     ((mu1 * mu1 + mu2 * mu2 + C1) * (v1 + v2 + C2));
        float l1 = fabsf(img1[idx] - trgb[idx]);

        float s_ssim = blk_reduce(ssim, smem);
        float s_l1 = blk_reduce(l1, smem);
        if (tid == 0) {
            ws[P_SSS + bid] = s_ssim;
            ws[P_SSL + bid] = s_l1;
        }
    }
    gbar(bar, 4);

    // ---------------- P6: final reduce (block 0) ----------------
    if (bid == 0) {
        float e = 0.f, d = 0.f, ss = 0.f, sl = 0.f;
        if (tid < 512) d = ws[P_L1D + tid];
        if (tid < 192) { ss = ws[P_SSS + tid]; sl = ws[P_SSL + tid]; }
        if (tid < 4) e = ws[P_ENT + tid];
        float rd_ = blk_reduce(d, smem);
        float rss = blk_reduce(ss, smem);
        float rsl = blk_reduce(sl, smem);
        float re = blk_reduce(e, smem);
        if (tid == 0) {
            float l1r = rsl / (float)(NB * 3 * HW);
            float ssim = rss / (float)(NB * 3 * HW);
            float l1d = rd_ / (float)(NB * HW);
            float opa = re / (float)(NB * NG);
            out[0] = 0.8f * l1r + 0.2f * (1.f - ssim) + 0.5f * l1d + 0.01f * opa;
        }
    }
}

extern "C" void kernel_launch(void* const* d_in, const int* in_sizes, int n_in,
                              void* d_out, int out_size, void* d_ws, size_t ws_size,
                              hipStream_t stream) {
    const float* g = (const float*)d_in[0];
    const float* intr = (const float*)d_in[1];
    const float* trgb = (const float*)d_in[2];
    const float* tdep = (const float*)d_in[3];
    float* ws = (float*)d_ws;
    float* out = (float*)d_out;

    // zero the grid-barrier state (ws is re-poisoned 0xAA before every launch)
    hipMemsetAsync((char*)d_ws + (size_t)BAR_OFF * 4, 0, 16 * 4, stream);

    void* args[] = {(void*)&g, (void*)&intr, (void*)&trgb, (void*)&tdep, (void*)&ws, (void*)&out};
    hipLaunchCooperativeKernel((void*)k_all, dim3(NBLK), dim3(512), args, 0, stream);
}

// Round 7
// 152.924 us; speedup vs baseline: 3.9388x; 3.9388x over previous
//
#include <hip/hip_runtime.h>

#define NB 2
#define NG 1024
#define HEIGHT 128
#define WIDTH 128
#define HW (HEIGHT * WIDTH)
#define NSEG 8
#define SEGLEN (NG / NSEG)                 // 128
#define ITEM_STRIDE (8 + (SEGLEN + 1) * 20)  // header + 128 items + trailing slot = 2588 floats
#define E10 4.5399931e-05f                 // exp(-10)

// ws layout (floats)
#define REC_U 0                            // unsorted records: 2048*16
#define ITEMS 67584                        // 16 streams * ITEM_STRIDE = 41408
#define RGBOF 108992                       // rendered rgb: 6*HW = 98304
#define P_ENT 207296                       // 2 entropy partials
#define P_L1D 207300                       // 512 depth-l1 partials
#define P_SSS 207812                       // 192 ssim partials
#define P_SSL 208004                       // 192 rgb-l1 partials
#define C_CNT 208200                       // int counter (memset to 0 in-stream)
// record (16 floats): [0]px [1]py [2]hx [3]hy [4]i00 [5]i01 [6]i11 [7]op [8]c0 [9]c1 [10]c2 [11]z
// item (5 quads): q0=[runT,runR,runG,runB] q1=[runD,px,py,op] q2=[hx,hy,i00,i01] q3=[i11,c0,c1,c2] q4=[z,-,-,-]

__device__ inline float blk_reduce(float v, float* sh) {
    for (int off = 32; off > 0; off >>= 1) v += __shfl_down(v, off, 64);
    int lane = threadIdx.x & 63;
    int w = threadIdx.x >> 6;
    __syncthreads();
    if (lane == 0) sh[w] = v;
    __syncthreads();
    float s = 0.f;
    if (threadIdx.x == 0) {
        int nw = (blockDim.x + 63) >> 6;
        for (int i = 0; i < nw; i++) s += sh[i];
    }
    return s;  // valid on thread 0 only
}

// ============ k_prep: preprocess + bitonic z-sort + segmented scan -> item streams ============
// One block per batch, 1024 threads (16 waves on one CU).
__global__ __launch_bounds__(1024) void k_prep(const float* __restrict__ g,
                                               const float* __restrict__ intr,
                                               float* __restrict__ ws) {
    __shared__ unsigned long long keys[NG];       // 8 KB: (z_bits<<32)|idx -> stable ascending sort
    __shared__ float sT[NG], sr[NG], sgc[NG], sb[NG], sd[NG];  // 20 KB scan state
    __shared__ int sf[NG], sx[NG];                // 8 KB
    __shared__ float rsh[16];
    int b = blockIdx.x;
    int tid = threadIdx.x;

    // ---- P1: per-gaussian preprocess (record in registers -> global REC_U) ----
    {
        int idx = (b << 10) + tid;
        const float* row = g + (size_t)idx * 38;
        float mx = row[0], my = row[1], mz = row[2];
        float sx_ = row[3], sy_ = row[4], sz_ = row[5];
        float qw = row[6], qx = row[7], qy = row[8], qz = row[9];
        float op = row[10];
        float sh0 = row[11], sh1 = row[12], sh2 = row[13];
        float fx = intr[b * 9 + 0], fy = intr[b * 9 + 4];
        float cx = intr[b * 9 + 2], cy = intr[b * 9 + 5];

        float z = fmaxf(mz, 1e-4f);
        float px = fx * mx / z + cx;
        float py = fy * my / z + cy;

        float r00 = 1.f - 2.f * (qy * qy + qz * qz), r01 = 2.f * (qx * qy - qw * qz), r02 = 2.f * (qx * qz + qw * qy);
        float r10 = 2.f * (qx * qy + qw * qz), r11 = 1.f - 2.f * (qx * qx + qz * qz), r12 = 2.f * (qy * qz - qw * qx);
        float r20 = 2.f * (qx * qz - qw * qy), r21 = 2.f * (qy * qz + qw * qx), r22 = 1.f - 2.f * (qx * qx + qy * qy);
        float a00 = r00 * sx_, a01 = r01 * sy_, a02 = r02 * sz_;
        float a10 = r10 * sx_, a11 = r11 * sy_, a12 = r12 * sz_;
        float a20 = r20 * sx_, a21 = r21 * sy_, a22 = r22 * sz_;
        float m00 = a00 * a00 + a01 * a01 + a02 * a02;
        float m01 = a00 * a10 + a01 * a11 + a02 * a12;
        float m02 = a00 * a20 + a01 * a21 + a02 * a22;
        float m11 = a10 * a10 + a11 * a11 + a12 * a12;
        float m12 = a10 * a20 + a11 * a21 + a12 * a22;
        float m22 = a20 * a20 + a21 * a21 + a22 * a22;

        float zc = fmaxf(mz, 1e-6f);
        float aJ = fx / zc, bJ = -fx * mx / (zc * zc);
        float cJ = fy / zc, dJ = -fy * my / (zc * zc);
        float c00 = aJ * aJ * m00 + 2.f * aJ * bJ * m02 + bJ * bJ * m22 + 0.3f;
        float c01 = cJ * (aJ * m01 + bJ * m12) + dJ * (aJ * m02 + bJ * m22);
        float c11 = cJ * cJ * m11 + 2.f * cJ * dJ * m12 + dJ * dJ * m22 + 0.3f;
        float det = fmaxf(c00 * c11 - c01 * c01, 1e-8f);
        float i00 = c11 / det;
        float i11 = c00 / det;
        float i01 = -c01 / det;

        const float C0c = 0.28209479177387814f;
        float col0 = fminf(fmaxf(sh0 * C0c + 0.5f, 0.f), 1.f);
        float col1 = fminf(fmaxf(sh1 * C0c + 0.5f, 0.f), 1.f);
        float col2 = fminf(fmaxf(sh2 * C0c + 0.5f, 0.f), 1.f);

        float hx = sqrtf(20.f * c00);
        float hy = sqrtf(20.f * c11);

        float* rec = ws + REC_U + (size_t)idx * 16;
        ((float4*)rec)[0] = make_float4(px, py, hx, hy);
        ((float4*)rec)[1] = make_float4(i00, i01, i11, op);
        ((float4*)rec)[2] = make_float4(col0, col1, col2, z);

        // z > 0 always (uniform 0.5..4) -> float bits are order-preserving as uint.
        keys[tid] = ((unsigned long long)__float_as_uint(z) << 32) | (unsigned int)tid;

        float o = fminf(fmaxf(op, 1e-6f), 1.f - 1e-6f);
        float ent = -(o * logf(o) + (1.f - o) * logf(1.f - o));
        float s = blk_reduce(ent, rsh);
        if (tid == 0) ws[P_ENT + b] = s;
    }
    __syncthreads();

    // ---- P2: bitonic sort of (z,idx) keys (stable == jnp.argsort) ----
    for (int k = 2; k <= NG; k <<= 1) {
        for (int j = k >> 1; j > 0; j >>= 1) {
            int ixj = tid ^ j;
            if (ixj > tid) {
                unsigned long long a = keys[tid], c = keys[ixj];
                bool up = ((tid & k) == 0);
                if ((a > c) == up) { keys[tid] = c; keys[ixj] = a; }
            }
            __syncthreads();
        }
    }

    // ---- P3: gather sorted record, segmented scan (8 segs x 128), emit item streams ----
    int gidx = (int)(keys[tid] & 1023u);
    const float* r = ws + REC_U + (size_t)((b << 10) + gidx) * 16;  // same-CU writes, visible after barrier
    float4 q0 = ((const float4*)r)[0];  // px py hx hy
    float4 q1 = ((const float4*)r)[1];  // i00 i01 i11 op
    float4 q2 = ((const float4*)r)[2];  // c0 c1 c2 z
    float a10 = E10 * q1.w;
    bool act = (q0.x + q0.z >= 0.f) && (q0.x - q0.z <= 127.f) &&
               (q0.y + q0.w >= 0.f) && (q0.y - q0.w <= 127.f);
    int k_ = tid & (SEGLEN - 1);
    int seg = tid >> 7;
    if (act) {
        sT[tid] = 1.f; sr[tid] = 0.f; sgc[tid] = 0.f; sb[tid] = 0.f; sd[tid] = 0.f;
        sf[tid] = 1; sx[tid] = 1;
    } else {
        sT[tid] = 1.f - a10;
        sr[tid] = a10 * q2.x; sgc[tid] = a10 * q2.y; sb[tid] = a10 * q2.z; sd[tid] = a10 * q2.w;
        sf[tid] = 0; sx[tid] = 0;
    }
    __syncthreads();
#pragma unroll
    for (int off = 1; off < SEGLEN; off <<= 1) {
        float pT = 1.f, pr = 0.f, pg = 0.f, pb = 0.f, pd = 0.f;
        int pf = 0, px_ = 0;
        bool doit = (k_ >= off);
        if (doit) {
            pT = sT[tid - off]; pr = sr[tid - off]; pg = sgc[tid - off];
            pb = sb[tid - off]; pd = sd[tid - off]; pf = sf[tid - off]; px_ = sx[tid - off];
        }
        __syncthreads();
        if (doit) {
            sx[tid] += px_;
            if (!sf[tid]) {  // absorb left partial unless a segment-start lies inside
                sr[tid] = pr + pT * sr[tid];
                sgc[tid] = pg + pT * sgc[tid];
                sb[tid] = pb + pT * sb[tid];
                sd[tid] = pd + pT * sd[tid];
                sT[tid] = pT * sT[tid];
                sf[tid] = pf;
            }
        }
        __syncthreads();
    }
    float* so = ws + ITEMS + (size_t)(b * NSEG + seg) * ITEM_STRIDE;
    int segend = (seg << 7) | (SEGLEN - 1);
    int n = sx[segend];
    if (act) {
        float* itp = so + 8 + (size_t)(sx[tid] - 1) * 20;
        float rT = 1.f, rr = 0.f, rg = 0.f, rb = 0.f, rd = 0.f;
        if (k_ > 0) { rT = sT[tid - 1]; rr = sr[tid - 1]; rg = sgc[tid - 1]; rb = sb[tid - 1]; rd = sd[tid - 1]; }
        ((float4*)itp)[0] = make_float4(rT, rr, rg, rb);
        ((float4*)itp)[1] = make_float4(rd, q0.x, q0.y, q1.w);
        ((float4*)itp)[2] = make_float4(q0.z, q0.w, q1.x, q1.y);
        ((float4*)itp)[3] = make_float4(q1.z, q2.x, q2.y, q2.z);
        ((float4*)itp)[4] = make_float4(q2.w, 0.f, 0.f, 0.f);
    }
    if (k_ == SEGLEN - 1) {  // trailing run -> slot n (fill all quads so prefetch reads defined data)
        float* itp = so + 8 + (size_t)n * 20;
        ((float4*)itp)[0] = make_float4(sT[tid], sr[tid], sgc[tid], sb[tid]);
        ((float4*)itp)[1] = make_float4(sd[tid], 0.f, 0.f, 0.f);
        ((float4*)itp)[2] = make_float4(0.f, 0.f, 0.f, 0.f);
        ((float4*)itp)[3] = make_float4(0.f, 0.f, 0.f, 0.f);
        ((float4*)itp)[4] = make_float4(0.f, 0.f, 0.f, 0.f);
    }
    if (k_ == 0) ((int*)so)[0] = n;
}

// ============ k_render: one 8x8 tile per block, 8 z-segment waves ============
__global__ __launch_bounds__(512) void k_render(const float* __restrict__ tgt_d,
                                                float* __restrict__ ws) {
    __shared__ float comb[5][512];
    int tid = threadIdx.x;
    int lane = tid & 63;
    int seg = tid >> 6;
    int blk = blockIdx.x;  // 512 tiles
    int b = blk >> 8;
    int t = blk & 255;
    int x0 = (t & 15) * 8, y0 = (t >> 4) * 8;
    int x = x0 + (lane & 7), y = y0 + (lane >> 3);

    const float* base = ws + ITEMS + (size_t)(b * NSEG + seg) * ITEM_STRIDE;
    int n = ((const int*)base)[0];
    const float4* ip = (const float4*)(base + 8);

    float xf = (float)x, yf = (float)y;
    float x0f = (float)x0, x1f = (float)(x0 + 7);
    float y0f = (float)y0, y1f = (float)(y0 + 7);
    float4 a0 = ip[0], a1 = ip[1], a2 = ip[2], a3 = ip[3], a4 = ip[4];
    float T = 1.f, cr = 0.f, cg_ = 0.f, cb = 0.f, cd = 0.f;
    for (int i = 0; i < n; i++) {
        const float4* np = ip + 5;
        float4 b0 = np[0], b1 = np[1], b2 = np[2], b3 = np[3], b4 = np[4];  // prefetch next
        cr += T * a0.y; cg_ += T * a0.z; cb += T * a0.w; cd += T * a1.x;
        T *= a0.x;
        float px = a1.y, py = a1.z, op = a1.w;
        float hx = a2.x, hy = a2.y;
        float alpha;
        if (px + hx >= x0f && px - hx <= x1f && py + hy >= y0f && py - hy <= y1f) {
            float dx = xf - px, dy = yf - py;
            float q = a2.z * dx * dx + 2.f * a2.w * dx * dy + a3.x * dy * dy;
            float pw = fminf(fmaxf(-0.5f * q, -10.f), 0.f);
            alpha = fminf(__expf(pw) * op, 0.99f);
        } else {
            alpha = E10 * op;  // clamped outside its ellipse: pixel-independent
        }
        float w = T * alpha;
        cr += w * a3.y; cg_ += w * a3.z; cb += w * a3.w; cd += w * a4.x;
        T -= w;
        a0 = b0; a1 = b1; a2 = b2; a3 = b3; a4 = b4;
        ip = np;
    }
    cr += T * a0.y; cg_ += T * a0.z; cb += T * a0.w; cd += T * a1.x;
    T *= a0.x;

    comb[0][tid] = T;
    comb[1][tid] = cr;
    comb[2][tid] = cg_;
    comb[3][tid] = cb;
    comb[4][tid] = cd;
    __syncthreads();

    if (tid < 64) {
        float T0 = comb[0][tid], r0 = comb[1][tid], g0 = comb[2][tid];
        float b0 = comb[3][tid], d0 = comb[4][tid];
#pragma unroll
        for (int sgi = 1; sgi < NSEG; sgi++) {
            int j = sgi * 64 + tid;
            r0 += T0 * comb[1][j];
            g0 += T0 * comb[2][j];
            b0 += T0 * comb[3][j];
            d0 += T0 * comb[4][j];
            T0 *= comb[0][j];
        }
        r0 = fminf(fmaxf(r0, 0.f), 1.f);
        g0 = fminf(fmaxf(g0, 0.f), 1.f);
        b0 = fminf(fmaxf(b0, 0.f), 1.f);
        float* rgb = ws + RGBOF;
        rgb[((b * 3 + 0) * HEIGHT + y) * WIDTH + x] = r0;
        rgb[((b * 3 + 1) * HEIGHT + y) * WIDTH + x] = g0;
        rgb[((b * 3 + 2) * HEIGHT + y) * WIDTH + x] = b0;
        float l1d = fabsf(d0 - tgt_d[(b * HEIGHT + y) * WIDTH + x]);
        for (int off = 32; off > 0; off >>= 1) l1d += __shfl_down(l1d, off, 64);
        if (tid == 0) ws[P_L1D + blk] = l1d;
    }
}

// ============ k_ssim: SSIM + rgb L1 + last-block final combine ============
__global__ __launch_bounds__(512) void k_ssim(const float* __restrict__ trgb,
                                              float* __restrict__ ws,
                                              float* __restrict__ out) {
    __shared__ float rsh[8];
    __shared__ int lastflag;
    int bid = blockIdx.x;
    int tid = threadIdx.x;
    int idx = bid * 512 + tid;  // < 98304 exact
    const float* img1 = ws + RGBOF;
    int bc = idx >> 14;
    int pix = idx & (HW - 1);
    int y = pix >> 7, x = pix & 127;

    float gg[7];
    float gs = 0.f;
#pragma unroll
    for (int i = 0; i < 7; i++) {
        float c = (float)(i - 3);
        gg[i] = __expf(-c * c / 4.5f);
        gs += gg[i];
    }
#pragma unroll
    for (int i = 0; i < 7; i++) gg[i] /= gs;

    float mu1 = 0.f, mu2 = 0.f, s11 = 0.f, s22 = 0.f, s12 = 0.f;
    int plane = bc * HW;
#pragma unroll
    for (int dy = -3; dy <= 3; dy++) {
        int yy = y + dy;
#pragma unroll
        for (int dx = -3; dx <= 3; dx++) {
            int xx = x + dx;
            float w = gg[dy + 3] * gg[dx + 3];
            float i1 = 0.f, i2 = 0.f;
            if (yy >= 0 && yy < HEIGHT && xx >= 0 && xx < WIDTH) {
                int o = plane + yy * WIDTH + xx;
                i1 = img1[o];
                i2 = trgb[o];
            }
            mu1 += w * i1;
            mu2 += w * i2;
            s11 += w * i1 * i1;
            s22 += w * i2 * i2;
            s12 += w * i1 * i2;
        }
    }
    float v1 = s11 - mu1 * mu1;
    float v2 = s22 - mu2 * mu2;
    float cv = s12 - mu1 * mu2;
    const float C1 = 1e-4f, C2 = 9e-4f;
    float ssim = ((2.f * mu1 * mu2 + C1) * (2.f * cv + C2)) /
                 ((mu1 * mu1 + mu2 * mu2 + C1) * (v1 + v2 + C2));
    float l1 = fabsf(img1[idx] - trgb[idx]);

    float s_ssim = blk_reduce(ssim, rsh);
    float s_l1 = blk_reduce(l1, rsh);
    if (tid == 0) {
        ws[P_SSS + bid] = s_ssim;
        ws[P_SSL + bid] = s_l1;
        __threadfence();  // release partials before counter bump
        int done = __hip_atomic_fetch_add((int*)(ws + C_CNT), 1, __ATOMIC_ACQ_REL,
                                          __HIP_MEMORY_SCOPE_AGENT);
        lastflag = (done == 191);
    }
    __syncthreads();
    if (lastflag) {
        __threadfence();  // acquire side
        float e = 0.f, d = 0.f, ss = 0.f, sl = 0.f;
        if (tid < 512) d = ws[P_L1D + tid];
        if (tid < 192) { ss = ws[P_SSS + tid]; sl = ws[P_SSL + tid]; }
        if (tid < 2) e = ws[P_ENT + tid];
        float rd_ = blk_reduce(d, rsh);
        float rss = blk_reduce(ss, rsh);
        float rsl = blk_reduce(sl, rsh);
        float re = blk_reduce(e, rsh);
        if (tid == 0) {
            float l1r = rsl / (float)(NB * 3 * HW);
            float ssimv = rss / (float)(NB * 3 * HW);
            float l1d = rd_ / (float)(NB * HW);
            float opa = re / (float)(NB * NG);
            out[0] = 0.8f * l1r + 0.2f * (1.f - ssimv) + 0.5f * l1d + 0.01f * opa;
        }
    }
}

extern "C" void kernel_launch(void* const* d_in, const int* in_sizes, int n_in,
                              void* d_out, int out_size, void* d_ws, size_t ws_size,
                              hipStream_t stream) {
    const float* g = (const float*)d_in[0];
    const float* intr = (const float*)d_in[1];
    const float* trgb = (const float*)d_in[2];
    const float* tdep = (const float*)d_in[3];
    float* ws = (float*)d_ws;
    float* out = (float*)d_out;

    // zero the last-block counter (ws is re-poisoned 0xAA before every launch)
    hipMemsetAsync((char*)d_ws + (size_t)C_CNT * 4, 0, 16, stream);

    hipLaunchKernelGGL(k_prep, dim3(NB), dim3(1024), 0, stream, g, intr, ws);
    hipLaunchKernelGGL(k_render, dim3(NB * 256), dim3(512), 0, stream, tdep, ws);
    hipLaunchKernelGGL(k_ssim, dim3(192), dim3(512), 0, stream, trgb, ws, out);
}